// Round 12
// baseline (26.441 us; speedup 1.0000x reference)
//
#include <hip/hip_runtime.h>
#include <math.h>

#define RESN 2048
#define TEXW 1024

// atan2 for y >= 0, returns [0, pi]. Cephes-style: min/max ratio + pi/8
// reduction + 4-term odd minimax + 1 Newton step on rcp. Peak err ~2e-7 rad.
__device__ __forceinline__ float fatan2_pos(float y, float x) {
    float ax = fabsf(x);
    float mn = fminf(ax, y);
    float mx = fmaxf(ax, y);
    float r0 = __builtin_amdgcn_rcpf(mx);
    r0 = r0 * __builtin_fmaf(-mx, r0, 2.0f);        // 1 Newton step -> ~0.5 ulp
    float a = mn * r0;                               // in [0,1]
    bool red = a > 0.41421356f;
    float t = (a - 1.0f) * __builtin_amdgcn_rcpf(a + 1.0f);
    float w = red ? t : a;                           // |w| <= 0.41421356
    float s = w * w;
    float p = __builtin_fmaf(s, 8.05374449538e-2f, -1.38776856032e-1f);
    p = __builtin_fmaf(s, p, 1.99777106478e-1f);
    p = __builtin_fmaf(s, p, -3.33329491539e-1f);
    float r = __builtin_fmaf(w * s, p, w);           // atan(w)
    r = red ? r + 0.78539816339f : r;                // + pi/4
    r = (y > ax) ? 1.57079632679f - r : r;
    r = (x < 0.0f) ? 3.14159265359f - r : r;
    return r;
}

// 12-byte texel -> global_load_dwordx3
struct __align__(4) F3 { float x, y, z; };

__global__ __launch_bounds__(256, 4) void egg_render(
    const float* __restrict__ tex,
    const float* __restrict__ nmap,
    float* __restrict__ out)
{
    // 2 px/thread software pipeline, flat scalars (no scratch), VGPR capped
    // at 128 (4 waves/SIMD). Schedule: addrA -> loadsA -> addrB (covers A's
    // flight, ~45 VALU) -> loadsB -> shadeA (covers B's flight, ~70 VALU)
    // -> shadeB. Stores: two 768B contiguous full-line bursts per wave.
    int t = blockIdx.x * 256 + threadIdx.x;          // 2,097,152 threads
    int j = t >> 10;                                  // row
    int tr = t & 1023;
    int iA = ((tr >> 6) << 7) + (tr & 63);            // first half of 128-px segment
    int iB = iA + 64;                                 // second half
    float* oA = out + ((size_t)j * RESN + iA) * 3u;
    float* oB = oA + 192u;

    const float invres = 1.0f / (float)RESN;
    // bit-exact vs numpy on the inside-test path: no fma contraction,
    // true IEEE division by 0.85
    float ny = __fmul_rn(__fsub_rn(0.5f, __fmul_rn((float)j, invres)), 2.0f) / 0.85f;
    float nysq = __fmul_rn(ny, ny);

    if (!(nysq <= 1.0f)) {                            // whole row outside
        oA[0] = 0.f; oA[1] = 0.f; oA[2] = 0.f;
        oB[0] = 0.f; oB[1] = 0.f; oB[2] = 0.f;
        return;
    }

    // ---- row-shared (ny-only) ----
    float egg = 1.0f - 0.25f * ny;                    // in [0.75, 1.25]
    float sphi = sqrtf(fmaxf(__builtin_fmaf(-ny, ny, 1.0f), 0.0f));
    float phi = fatan2_pos(sphi, ny);                 // == acos(ny)
    float v = phi * 0.3183098861837907f;              // /pi, in [0,1]; floor provably unneeded
    float yy = v * (float)TEXW - 0.5f;
    float yf = floorf(yy);
    float fy = yy - yf;
    float gy = 1.0f - fy;
    int y0 = (int)yf & (TEXW - 1);
    int y1 = (y0 + 1) & (TEXW - 1);
    int rb0 = y0 * TEXW;
    int rb1 = y1 * TEXW;

    // ---- pixel A: address math ----
    float nxA = __fmul_rn(__fsub_rn(__fmul_rn((float)iA, invres), 0.5f), 2.0f) / 0.85f;
    float rsqA = __fadd_rn(__fmul_rn(nxA, nxA), nysq);
    bool inA = (rsqA <= 1.0f);
    float zA = sqrtf(fmaxf(__fsub_rn(1.0f, rsqA), 0.0f));   // 0 for outside lanes
    float thetaA = fatan2_pos(zA, nxA);                      // outside lanes: valid addr anyway
    float uA = thetaA * 0.15915494309189535f + 0.5f;         // in [0.5,1.0]
    float xxA = uA * (float)TEXW - 0.5f;
    float xfA = floorf(xxA);
    float fxA = xxA - xfA;
    float gxA = 1.0f - fxA;
    int x0A = (int)xfA & (TEXW - 1);
    int x1A = (x0A + 1) & (TEXW - 1);
    float w00A = gxA * gy, w01A = fxA * gy, w10A = gxA * fy, w11A = fxA * fy;
    int o00A = (rb0 + x0A) * 3, o01A = (rb0 + x1A) * 3;
    int o10A = (rb1 + x0A) * 3, o11A = (rb1 + x1A) * 3;

    // ---- issue A's 8 gathers; B's address math below covers their flight ----
    F3 aA00 = *(const F3*)(tex + o00A);
    F3 aA01 = *(const F3*)(tex + o01A);
    F3 aA10 = *(const F3*)(tex + o10A);
    F3 aA11 = *(const F3*)(tex + o11A);
    F3 nA00 = *(const F3*)(nmap + o00A);
    F3 nA01 = *(const F3*)(nmap + o01A);
    F3 nA10 = *(const F3*)(nmap + o10A);
    F3 nA11 = *(const F3*)(nmap + o11A);

    // ---- pixel B: address math (~45 VALU ops of latency cover for A) ----
    float nxB = __fmul_rn(__fsub_rn(__fmul_rn((float)iB, invres), 0.5f), 2.0f) / 0.85f;
    float rsqB = __fadd_rn(__fmul_rn(nxB, nxB), nysq);
    bool inB = (rsqB <= 1.0f);
    float zB = sqrtf(fmaxf(__fsub_rn(1.0f, rsqB), 0.0f));
    float thetaB = fatan2_pos(zB, nxB);
    float uB = thetaB * 0.15915494309189535f + 0.5f;
    float xxB = uB * (float)TEXW - 0.5f;
    float xfB = floorf(xxB);
    float fxB = xxB - xfB;
    float gxB = 1.0f - fxB;
    int x0B = (int)xfB & (TEXW - 1);
    int x1B = (x0B + 1) & (TEXW - 1);
    float w00B = gxB * gy, w01B = fxB * gy, w10B = gxB * fy, w11B = fxB * fy;
    int o00B = (rb0 + x0B) * 3, o01B = (rb0 + x1B) * 3;
    int o10B = (rb1 + x0B) * 3, o11B = (rb1 + x1B) * 3;

    // ---- issue B's 8 gathers; shade A covers their flight ----
    F3 aB00 = *(const F3*)(tex + o00B);
    F3 aB01 = *(const F3*)(tex + o01B);
    F3 aB10 = *(const F3*)(tex + o10B);
    F3 aB11 = *(const F3*)(tex + o11B);
    F3 nB00 = *(const F3*)(nmap + o00B);
    F3 nB01 = *(const F3*)(nmap + o01B);
    F3 nB10 = *(const F3*)(nmap + o10B);
    F3 nB11 = *(const F3*)(nmap + o11B);

    // lighting constants (compile-time folded, f32 semantics)
    float Lx = 0.5f, Ly = 0.7f, Lz = 1.0f;
    float ll = sqrtf(Lx * Lx + Ly * Ly + Lz * Lz);
    Lx /= ll; Ly /= ll; Lz /= ll;
    float Hx = Lx, Hy = Ly, Hz = Lz + 1.0f;
    float hl = sqrtf(Hx * Hx + Hy * Hy + Hz * Hz);
    Hx /= hl; Hy /= hl; Hz /= hl;

    // ---- shade A (waits vmcnt(8): only A's loads; B's stay in flight) ----
    {
        float ar = aA00.x*w00A + aA01.x*w01A + aA10.x*w10A + aA11.x*w11A;
        float ag = aA00.y*w00A + aA01.y*w01A + aA10.y*w10A + aA11.y*w11A;
        float ab = aA00.z*w00A + aA01.z*w01A + aA10.z*w10A + aA11.z*w11A;
        float tnx = (nA00.x*w00A + nA01.x*w01A + nA10.x*w10A + nA11.x*w11A) * 2.0f - 1.0f;
        float tny = (nA00.y*w00A + nA01.y*w01A + nA10.y*w10A + nA11.y*w11A) * 2.0f - 1.0f;
        float tnz = (nA00.z*w00A + nA01.z*w01A + nA10.z*w10A + nA11.z*w11A) * 2.0f - 1.0f;

        float snx = nxA * egg, sny = ny, snz = zA * egg;
        float sl2 = snx*snx + sny*sny + snz*snz;       // > 0.5 even for outside lanes
        float isl = __builtin_amdgcn_rsqf(sl2);
        float bnx = snx * isl, bny = sny * isl, bnz = snz * isl;

        bool use_right = fabsf(bny) > 0.99f;
        float d = use_right ? bnx : bny;
        float m = use_right ? bny : bnx;
        float q2 = m * m + bnz * bnz;
        float iq = __builtin_amdgcn_rsqf(q2);
        float q  = q2 * iq;
        float e  = -(d * iq);
        float tzv = bnz * e;
        float tx = use_right ? q : (bnx * e);
        float ty = use_right ? (bny * e) : q;
        float bx = use_right ? 0.0f        : -(bnz * iq);
        float by = use_right ? (bnz * iq)  : 0.0f;
        float bz = use_right ? -(bny * iq) : (bnx * iq);

        float wx = tnx * tx + tny * bx + tnz * bnx;
        float wy = tnx * ty + tny * by + tnz * bny;
        float wz = tnx * tzv + tny * bz + tnz * bnz;
        float wl2 = wx*wx + wy*wy + wz*wz;
        float iwl = __builtin_amdgcn_rsqf(fmaxf(wl2, 1e-12f));
        wx *= iwl; wy *= iwl; wz *= iwl;

        float ndotl = fmaxf(wx * Lx + wy * Ly + wz * Lz, 0.0f);
        float ndoth = fmaxf(wx * Hx + wy * Hy + wz * Hz, 0.0f);
        float s2 = ndoth * ndoth, s4 = s2 * s2, s8 = s4 * s4, s16 = s8 * s8;
        float spec = s16 * s16;
        float ndotv = fmaxf(wz, 0.0f);
        float t1 = 1.0f - ndotv;
        float t2 = t1 * t1, t4 = t2 * t2;
        float fres = 0.04f + 0.96f * (t4 * t1);
        float ka = 0.1f + ndotl;
        float add = spec * fres;

        oA[0] = inA ? fminf(fmaxf(__builtin_fmaf(ar, ka, add), 0.0f), 1.0f) : 0.0f;
        oA[1] = inA ? fminf(fmaxf(__builtin_fmaf(ag, ka, add), 0.0f), 1.0f) : 0.0f;
        oA[2] = inA ? fminf(fmaxf(__builtin_fmaf(ab, ka, add), 0.0f), 1.0f) : 0.0f;
    }

    // ---- shade B ----
    {
        float ar = aB00.x*w00B + aB01.x*w01B + aB10.x*w10B + aB11.x*w11B;
        float ag = aB00.y*w00B + aB01.y*w01B + aB10.y*w10B + aB11.y*w11B;
        float ab = aB00.z*w00B + aB01.z*w01B + aB10.z*w10B + aB11.z*w11B;
        float tnx = (nB00.x*w00B + nB01.x*w01B + nB10.x*w10B + nB11.x*w11B) * 2.0f - 1.0f;
        float tny = (nB00.y*w00B + nB01.y*w01B + nB10.y*w10B + nB11.y*w11B) * 2.0f - 1.0f;
        float tnz = (nB00.z*w00B + nB01.z*w01B + nB10.z*w10B + nB11.z*w11B) * 2.0f - 1.0f;

        float snx = nxB * egg, sny = ny, snz = zB * egg;
        float sl2 = snx*snx + sny*sny + snz*snz;
        float isl = __builtin_amdgcn_rsqf(sl2);
        float bnx = snx * isl, bny = sny * isl, bnz = snz * isl;

        bool use_right = fabsf(bny) > 0.99f;
        float d = use_right ? bnx : bny;
        float m = use_right ? bny : bnx;
        float q2 = m * m + bnz * bnz;
        float iq = __builtin_amdgcn_rsqf(q2);
        float q  = q2 * iq;
        float e  = -(d * iq);
        float tzv = bnz * e;
        float tx = use_right ? q : (bnx * e);
        float ty = use_right ? (bny * e) : q;
        float bx = use_right ? 0.0f        : -(bnz * iq);
        float by = use_right ? (bnz * iq)  : 0.0f;
        float bz = use_right ? -(bny * iq) : (bnx * iq);

        float wx = tnx * tx + tny * bx + tnz * bnx;
        float wy = tnx * ty + tny * by + tnz * bny;
        float wz = tnx * tzv + tny * bz + tnz * bnz;
        float wl2 = wx*wx + wy*wy + wz*wz;
        float iwl = __builtin_amdgcn_rsqf(fmaxf(wl2, 1e-12f));
        wx *= iwl; wy *= iwl; wz *= iwl;

        float ndotl = fmaxf(wx * Lx + wy * Ly + wz * Lz, 0.0f);
        float ndoth = fmaxf(wx * Hx + wy * Hy + wz * Hz, 0.0f);
        float s2 = ndoth * ndoth, s4 = s2 * s2, s8 = s4 * s4, s16 = s8 * s8;
        float spec = s16 * s16;
        float ndotv = fmaxf(wz, 0.0f);
        float t1 = 1.0f - ndotv;
        float t2 = t1 * t1, t4 = t2 * t2;
        float fres = 0.04f + 0.96f * (t4 * t1);
        float ka = 0.1f + ndotl;
        float add = spec * fres;

        oB[0] = inB ? fminf(fmaxf(__builtin_fmaf(ar, ka, add), 0.0f), 1.0f) : 0.0f;
        oB[1] = inB ? fminf(fmaxf(__builtin_fmaf(ag, ka, add), 0.0f), 1.0f) : 0.0f;
        oB[2] = inB ? fminf(fmaxf(__builtin_fmaf(ab, ka, add), 0.0f), 1.0f) : 0.0f;
    }
}

extern "C" void kernel_launch(void* const* d_in, const int* in_sizes, int n_in,
                              void* d_out, int out_size, void* d_ws, size_t ws_size,
                              hipStream_t stream) {
    const float* tex  = (const float*)d_in[0];
    const float* nmap = (const float*)d_in[1];
    float* out = (float*)d_out;
    int total_threads = RESN * RESN / 2;          // 2,097,152
    dim3 grid(total_threads / 256), block(256);   // 8192 blocks
    hipLaunchKernelGGL(egg_render, grid, block, 0, stream, tex, nmap, out);
}